// Round 7
// baseline (374.623 us; speedup 1.0000x reference)
//
#include <hip/hip_runtime.h>

#define N_NODES 50000
#define N_EDGES 800000
#define IN_F 96
#define HID_F 128
#define OUT_F 64
#define T_S 8
#define CAP 48  // bucket capacity per node; Poisson(16) tail P[deg>48] < 1e-10

// fused-prep block ranges (cursor zero + xb convert + weight prep)
#define NB_ZERO 196     // ceil(50000/256)
#define NB_XB 4688      // ceil(50000*96/4/256)
#define NB_WPREP 640    // 8*20480/256
#define NB_PREP (NB_ZERO + NB_XB + NB_WPREP)

typedef __attribute__((ext_vector_type(8))) short short8;
typedef __attribute__((ext_vector_type(4))) float float4v;
typedef __attribute__((ext_vector_type(2))) float float2v;
typedef __attribute__((ext_vector_type(2))) unsigned uint2v;
typedef __attribute__((ext_vector_type(4))) unsigned uint4v;
typedef __attribute__((ext_vector_type(2))) int int2v;

__device__ __forceinline__ float bf2f(unsigned short h) {
    unsigned u = ((unsigned)h) << 16;
    float f;
    __builtin_memcpy(&f, &u, 4);
    return f;
}
__device__ __forceinline__ unsigned short f2bf(float f) {
    unsigned u;
    __builtin_memcpy(&u, &f, 4);
    unsigned r = (u + 0x7fffu + ((u >> 16) & 1u)) >> 16;  // RTNE
    return (unsigned short)r;
}
__device__ __forceinline__ float bf_lo(unsigned u) {
    unsigned v = u << 16;
    float f;
    __builtin_memcpy(&f, &v, 4);
    return f;
}
__device__ __forceinline__ float bf_hi(unsigned u) {
    unsigned v = u & 0xffff0000u;
    float f;
    __builtin_memcpy(&f, &v, 4);
    return f;
}

// ---------------- Fused prep: cursor zero + x->bf16 + weight prep ----------------
// Independent jobs partitioned by blockIdx range; cursor is zeroed before k_fillB
// launches (stream order), so no separate memset dispatch is needed.
__global__ __launch_bounds__(256) void k_prep(int* __restrict__ cursor,
                                              const float* __restrict__ x,
                                              unsigned short* __restrict__ xb,
                                              const float* __restrict__ W1,
                                              const float* __restrict__ W2,
                                              const float* __restrict__ m1,
                                              const float* __restrict__ m2,
                                              unsigned short* __restrict__ wf) {
    int bid = blockIdx.x;
    if (bid < NB_ZERO) {
        int i = bid * 256 + threadIdx.x;
        if (i < N_NODES) cursor[i] = 0;
        return;
    }
    bid -= NB_ZERO;
    if (bid < NB_XB) {
        int i = bid * 256 + threadIdx.x;
        int idx = i * 4;
        if (idx < N_NODES * IN_F) {
            float4v v = __builtin_nontemporal_load((const float4v*)(x + idx));
            uint2v r;
            r.x = (unsigned)f2bf(v.x) | ((unsigned)f2bf(v.y) << 16);
            r.y = (unsigned)f2bf(v.z) | ((unsigned)f2bf(v.w) << 16);
            *(uint2v*)(xb + idx) = r;
        }
        return;
    }
    bid -= NB_XB;
    {
        int gid = bid * 256 + threadIdx.x;  // 8*20480 = 163840 total
        if (gid >= T_S * 20480) return;
        int t = gid / 20480;
        int idx = gid % 20480;
        float val;
        if (idx < 12288) {
            int j = idx & 7, lane = (idx >> 3) & 63, fr = idx >> 9;  // fr 0..23
            int kk = fr >> 3, nt = fr & 7;
            int k = kk * 32 + (lane >> 4) * 8 + j;
            int n = nt * 16 + (lane & 15);
            val = W1[k * HID_F + n] * m1[((size_t)t * IN_F + k) * HID_F + n];
        } else {
            int i2 = idx - 12288;
            int j = i2 & 7, lane = (i2 >> 3) & 63, fr = i2 >> 9;  // fr 0..15
            int kk = fr >> 2, ot = fr & 3;
            int k = kk * 32 + (lane >> 4) * 8 + j;
            int o = ot * 16 + (lane & 15);
            val = W2[k * OUT_F + o] * m2[((size_t)t * HID_F + k) * OUT_F + o];
        }
        wf[gid] = f2bf(val);
    }
}

// ---------------- Bucket fill: 2 edges/thread, vectorized 8B loads ----------------
// cursor doubles as the per-node degree count (no count/scan passes needed).
__global__ __launch_bounds__(256) void k_fillB(const int* __restrict__ src,
                                               const int* __restrict__ dst,
                                               const float* __restrict__ ew,
                                               int* __restrict__ cursor,
                                               uint2v* __restrict__ bucket) {
    int e = (blockIdx.x * 256 + threadIdx.x) * 2;
    if (e + 1 < N_EDGES) {
        int2v s2 = *(const int2v*)(src + e);
        int2v d2 = *(const int2v*)(dst + e);
        float2v w2 = *(const float2v*)(ew + e);
        int p0 = atomicAdd(&cursor[d2.x], 1);
        if (p0 < CAP) {
            uint2v c;
            c.x = (unsigned)s2.x;
            c.y = __float_as_uint(w2.x);
            __builtin_nontemporal_store(c, &bucket[(size_t)d2.x * CAP + p0]);
        }
        int p1 = atomicAdd(&cursor[d2.y], 1);
        if (p1 < CAP) {
            uint2v c;
            c.x = (unsigned)s2.y;
            c.y = __float_as_uint(w2.y);
            __builtin_nontemporal_store(c, &bucket[(size_t)d2.y * CAP + p1]);
        }
    } else if (e < N_EDGES) {
        int d = dst[e];
        int pos = atomicAdd(&cursor[d], 1);
        if (pos < CAP) {
            uint2v c;
            c.x = (unsigned)src[e];
            c.y = __float_as_uint(ew[e]);
            __builtin_nontemporal_store(c, &bucket[(size_t)d * CAP + pos]);
        }
    }
}

// ---------------- SPMM1: agg1 = spmm(xb), wave per node, dword gathers, unroll 8 ----------------
__global__ __launch_bounds__(256) void k_spmm1(const unsigned short* __restrict__ xb,
                                               const int* __restrict__ cursor,
                                               const uint2v* __restrict__ bucket,
                                               unsigned short* __restrict__ agg1) {
    int wave = threadIdx.x >> 6, lane = threadIdx.x & 63;
    int node = blockIdx.x * 4 + wave;
    if (lane >= 48) return;  // 48 dwords per 96-bf16 row
    int cnt = cursor[node];
    if (cnt > CAP) cnt = CAP;
    int beg = node * CAP, end = beg + cnt;
    const unsigned* xrow = (const unsigned*)xb;
    float a0 = 0.f, a1 = 0.f;
    int e = beg;
    for (; e + 7 < end; e += 8) {
        uint2v c[8];
        unsigned d[8];
#pragma unroll
        for (int i = 0; i < 8; i++) c[i] = bucket[e + i];
#pragma unroll
        for (int i = 0; i < 8; i++) d[i] = xrow[(size_t)c[i].x * 48 + lane];
#pragma unroll
        for (int i = 0; i < 8; i++) {
            float wv = __uint_as_float(c[i].y);
            a0 = fmaf(wv, bf_lo(d[i]), a0);
            a1 = fmaf(wv, bf_hi(d[i]), a1);
        }
    }
    for (; e + 3 < end; e += 4) {
        uint2v c[4];
        unsigned d[4];
#pragma unroll
        for (int i = 0; i < 4; i++) c[i] = bucket[e + i];
#pragma unroll
        for (int i = 0; i < 4; i++) d[i] = xrow[(size_t)c[i].x * 48 + lane];
#pragma unroll
        for (int i = 0; i < 4; i++) {
            float wv = __uint_as_float(c[i].y);
            a0 = fmaf(wv, bf_lo(d[i]), a0);
            a1 = fmaf(wv, bf_hi(d[i]), a1);
        }
    }
    for (; e < end; e++) {
        uint2v c = bucket[e];
        float wv = __uint_as_float(c.y);
        unsigned d = xrow[(size_t)c.x * 48 + lane];
        a0 = fmaf(wv, bf_lo(d), a0);
        a1 = fmaf(wv, bf_hi(d), a1);
    }
    ((unsigned*)agg1)[(size_t)node * 48 + lane] =
        (unsigned)f2bf(a0) | ((unsigned)f2bf(a1) << 16);
}

// ------------- Fused GEMM: p_t = relu(agg1 @ W1m_t) @ W2m_t, bf16 out -------------
// Grid dim3(8, 98): linear block id = t + 8*nb, so the %8 XCD round-robin pins each
// t to one XCD -> its 40KB weight slice stays L2-resident across all 98 node-blocks.
__global__ __launch_bounds__(256) void k_gemm(const unsigned short* __restrict__ agg1,
                                              const unsigned short* __restrict__ wfrags,
                                              unsigned short* __restrict__ P, int tBase,
                                              int nodeStride, int tMul) {
    __shared__ __align__(16) unsigned short ldsW[20480];     // 40 KB
    __shared__ __align__(16) unsigned short ldsH[4][2176];   // 4 waves x [16][136] bf16
    int t = tBase + blockIdx.x;
    const uint4* wsrc = (const uint4*)(wfrags + (size_t)t * 20480);
    uint4* wdst = (uint4*)ldsW;
    for (int i = threadIdx.x; i < 2560; i += 256) wdst[i] = wsrc[i];
    __syncthreads();

    int wave = threadIdx.x >> 6, lane = threadIdx.x & 63;
    int quad = lane >> 4, l15 = lane & 15;

    for (int it = 0; it < 8; it++) {
        int node = blockIdx.y * 512 + it * 64 + wave * 16 + l15;
        bool v = node < N_NODES;

        short8 a[3];
        if (v) {
            const unsigned short* ap = agg1 + (size_t)node * IN_F;
            a[0] = *(const short8*)(ap + 0 * 32 + quad * 8);
            a[1] = *(const short8*)(ap + 1 * 32 + quad * 8);
            a[2] = *(const short8*)(ap + 2 * 32 + quad * 8);
        } else {
            short8 z = {0, 0, 0, 0, 0, 0, 0, 0};
            a[0] = z; a[1] = z; a[2] = z;
        }

        for (int nt = 0; nt < 8; nt++) {
            float4v acc = {0.f, 0.f, 0.f, 0.f};
            for (int kk = 0; kk < 3; kk++) {
                short8 w = *(const short8*)&ldsW[(kk * 8 + nt) * 512 + lane * 8];
                acc = __builtin_amdgcn_mfma_f32_16x16x32_bf16(w, a[kk], acc, 0, 0, 0);
            }
            unsigned h0 = f2bf(fmaxf(acc[0], 0.f));
            unsigned h1 = f2bf(fmaxf(acc[1], 0.f));
            unsigned h2 = f2bf(fmaxf(acc[2], 0.f));
            unsigned h3 = f2bf(fmaxf(acc[3], 0.f));
            uint2 pk;
            pk.x = h0 | (h1 << 16);
            pk.y = h2 | (h3 << 16);
            *(uint2*)&ldsH[wave][l15 * 136 + nt * 16 + quad * 4] = pk;
        }

        short8 hf[4];
        for (int kk = 0; kk < 4; kk++)
            hf[kk] = *(const short8*)&ldsH[wave][l15 * 136 + kk * 32 + quad * 8];

        unsigned short* Pt = P + (size_t)node * nodeStride + (size_t)t * tMul;
        for (int ot = 0; ot < 4; ot++) {
            float4v acc = {0.f, 0.f, 0.f, 0.f};
            for (int kk = 0; kk < 4; kk++) {
                short8 w = *(const short8*)&ldsW[12288 + (kk * 4 + ot) * 512 + lane * 8];
                acc = __builtin_amdgcn_mfma_f32_16x16x32_bf16(w, hf[kk], acc, 0, 0, 0);
            }
            if (v) {
                uint2 pk;
                pk.x = (unsigned)f2bf(acc[0]) | ((unsigned)f2bf(acc[1]) << 16);
                pk.y = (unsigned)f2bf(acc[2]) | ((unsigned)f2bf(acc[3]) << 16);
                *(uint2*)(Pt + ot * 16 + quad * 4) = pk;
            }
        }
    }
}

// ------------- SPMM2 batched (proven form): P [node][t][o], 1KB rows, wave/node -------------
__global__ __launch_bounds__(256) void k_spmm2(const unsigned short* __restrict__ P,
                                               const int* __restrict__ cursor,
                                               const uint2v* __restrict__ bucket,
                                               float* __restrict__ out) {
    int wave = threadIdx.x >> 6, lane = threadIdx.x & 63;
    int node = blockIdx.x * 4 + wave;
    int cnt = cursor[node];
    if (cnt > CAP) cnt = CAP;
    int beg = node * CAP, end = beg + cnt;
    const uint4v* Pl = (const uint4v*)P + lane;  // row = 64 uint4
    float acc[8] = {0.f, 0.f, 0.f, 0.f, 0.f, 0.f, 0.f, 0.f};
    int e = beg;
    for (; e + 7 < end; e += 8) {
        uint2v c[8];
        uint4v d[8];
#pragma unroll
        for (int i = 0; i < 8; i++) c[i] = bucket[e + i];
#pragma unroll
        for (int i = 0; i < 8; i++) d[i] = Pl[(size_t)c[i].x * 64];
#pragma unroll
        for (int i = 0; i < 8; i++) {
            float wv = __uint_as_float(c[i].y);
            acc[0] = fmaf(wv, bf_lo(d[i].x), acc[0]);
            acc[1] = fmaf(wv, bf_hi(d[i].x), acc[1]);
            acc[2] = fmaf(wv, bf_lo(d[i].y), acc[2]);
            acc[3] = fmaf(wv, bf_hi(d[i].y), acc[3]);
            acc[4] = fmaf(wv, bf_lo(d[i].z), acc[4]);
            acc[5] = fmaf(wv, bf_hi(d[i].z), acc[5]);
            acc[6] = fmaf(wv, bf_lo(d[i].w), acc[6]);
            acc[7] = fmaf(wv, bf_hi(d[i].w), acc[7]);
        }
    }
    for (; e + 3 < end; e += 4) {
        uint2v c[4];
        uint4v d[4];
#pragma unroll
        for (int i = 0; i < 4; i++) c[i] = bucket[e + i];
#pragma unroll
        for (int i = 0; i < 4; i++) d[i] = Pl[(size_t)c[i].x * 64];
#pragma unroll
        for (int i = 0; i < 4; i++) {
            float wv = __uint_as_float(c[i].y);
            acc[0] = fmaf(wv, bf_lo(d[i].x), acc[0]);
            acc[1] = fmaf(wv, bf_hi(d[i].x), acc[1]);
            acc[2] = fmaf(wv, bf_lo(d[i].y), acc[2]);
            acc[3] = fmaf(wv, bf_hi(d[i].y), acc[3]);
            acc[4] = fmaf(wv, bf_lo(d[i].z), acc[4]);
            acc[5] = fmaf(wv, bf_hi(d[i].z), acc[5]);
            acc[6] = fmaf(wv, bf_lo(d[i].w), acc[6]);
            acc[7] = fmaf(wv, bf_hi(d[i].w), acc[7]);
        }
    }
    for (; e < end; e++) {
        uint2v c = bucket[e];
        float wv = __uint_as_float(c.y);
        uint4v d = Pl[(size_t)c.x * 64];
        acc[0] = fmaf(wv, bf_lo(d.x), acc[0]);
        acc[1] = fmaf(wv, bf_hi(d.x), acc[1]);
        acc[2] = fmaf(wv, bf_lo(d.y), acc[2]);
        acc[3] = fmaf(wv, bf_hi(d.y), acc[3]);
        acc[4] = fmaf(wv, bf_lo(d.z), acc[4]);
        acc[5] = fmaf(wv, bf_hi(d.z), acc[5]);
        acc[6] = fmaf(wv, bf_lo(d.w), acc[6]);
        acc[7] = fmaf(wv, bf_hi(d.w), acc[7]);
    }
    // lane covers value indices lane*8..+7 of the [t][o] row: t = lane>>3, o = (lane&7)*8
    int t = lane >> 3, o = (lane & 7) * 8;
    float* op = out + ((size_t)t * N_NODES + node) * OUT_F + o;
    float4v v0 = {acc[0], acc[1], acc[2], acc[3]};
    float4v v1 = {acc[4], acc[5], acc[6], acc[7]};
    *(float4v*)op = v0;
    *(float4v*)(op + 4) = v1;
}

// per-sample fallback (small workspace): P layout [node][64]
__global__ __launch_bounds__(512) void k_spmm2_1t(const unsigned short* __restrict__ P,
                                                  const int* __restrict__ cursor,
                                                  const uint2v* __restrict__ bucket,
                                                  float* __restrict__ out) {
    int node = blockIdx.x * 8 + (threadIdx.x >> 6);
    int o = threadIdx.x & 63;
    if (node >= N_NODES) return;
    int cnt = cursor[node];
    if (cnt > CAP) cnt = CAP;
    int beg = node * CAP, end = beg + cnt;
    const unsigned short* Pt = P + o;
    float a0 = 0.f, a1 = 0.f, a2 = 0.f, a3 = 0.f;
    int e = beg;
    for (; e + 3 < end; e += 4) {
        uint2v c0 = bucket[e];
        uint2v c1 = bucket[e + 1];
        uint2v c2 = bucket[e + 2];
        uint2v c3 = bucket[e + 3];
        a0 += __uint_as_float(c0.y) * bf2f(Pt[(size_t)c0.x * OUT_F]);
        a1 += __uint_as_float(c1.y) * bf2f(Pt[(size_t)c1.x * OUT_F]);
        a2 += __uint_as_float(c2.y) * bf2f(Pt[(size_t)c2.x * OUT_F]);
        a3 += __uint_as_float(c3.y) * bf2f(Pt[(size_t)c3.x * OUT_F]);
    }
    for (; e < end; e++) {
        uint2v c = bucket[e];
        a0 += __uint_as_float(c.y) * bf2f(Pt[(size_t)c.x * OUT_F]);
    }
    out[(size_t)node * OUT_F + o] = a0 + a1 + a2 + a3;
}

extern "C" void kernel_launch(void* const* d_in, const int* in_sizes, int n_in,
                              void* d_out, int out_size, void* d_ws, size_t ws_size,
                              hipStream_t stream) {
    const float* x = (const float*)d_in[0];
    const float* ew = (const float*)d_in[1];
    const float* W1 = (const float*)d_in[2];
    const float* W2 = (const float*)d_in[3];
    const float* m1 = (const float*)d_in[4];
    const float* m2 = (const float*)d_in[5];
    const int* src = (const int*)d_in[6];
    const int* dst = (const int*)d_in[7];
    float* out = (float*)d_out;

    char* w = (char*)d_ws;
    size_t off = 0;
    auto alloc = [&](size_t bytes) -> void* {
        void* p = (void*)(w + off);
        off += (bytes + 255) & ~(size_t)255;
        return p;
    };
    int* cursor = (int*)alloc((size_t)N_NODES * 4);
    uint2v* bucket = (uint2v*)alloc((size_t)N_NODES * CAP * 8);  // 19.2 MB
    unsigned short* agg1 = (unsigned short*)alloc((size_t)N_NODES * IN_F * 2);
    unsigned short* wf = (unsigned short*)alloc((size_t)T_S * 20480 * 2);

    // union region: xb (9.6 MB, dead before k_gemm) overlaps P (51.2 MB batched)
    size_t unionBase = off;
    size_t pBytesBatched = (size_t)T_S * N_NODES * OUT_F * 2;
    size_t xbBytes = (size_t)N_NODES * IN_F * 2;
    bool batched = ws_size >= unionBase + (pBytesBatched > xbBytes ? pBytesBatched : xbBytes);
    unsigned short* xb = (unsigned short*)(w + unionBase);
    unsigned short* P = (unsigned short*)(w + unionBase);
    if (!batched) {
        xb = (unsigned short*)(w + unionBase);
        P = (unsigned short*)(w + unionBase + ((xbBytes + 255) & ~(size_t)255));
    }

    k_prep<<<NB_PREP, 256, 0, stream>>>(cursor, x, xb, W1, W2, m1, m2, wf);
    k_fillB<<<(N_EDGES / 2 + 255) / 256, 256, 0, stream>>>(src, dst, ew, cursor, bucket);
    k_spmm1<<<N_NODES / 4, 256, 0, stream>>>(xb, cursor, bucket, agg1);

    if (batched) {
        k_gemm<<<dim3(8, 98), 256, 0, stream>>>(agg1, wf, P, 0, T_S * OUT_F, OUT_F);
        k_spmm2<<<N_NODES / 4, 256, 0, stream>>>(P, cursor, bucket, out);
    } else {
        for (int t = 0; t < T_S; t++) {
            k_gemm<<<dim3(1, 98), 256, 0, stream>>>(agg1, wf, P, t, OUT_F, 0);
            k_spmm2_1t<<<6250, 512, 0, stream>>>(P, cursor, bucket,
                                                 out + (size_t)t * N_NODES * OUT_F);
        }
    }
}

// Round 8
// 362.354 us; speedup vs baseline: 1.0339x; 1.0339x over previous
//
#include <hip/hip_runtime.h>

#define N_NODES 50000
#define N_EDGES 800000
#define IN_F 96
#define HID_F 128
#define OUT_F 64
#define T_S 8
#define CAP 48  // bucket capacity per node; Poisson(16) tail P[deg>48] < 1e-10

// fused-prep block ranges (cursor zero + xb convert + weight prep)
#define NB_ZERO 196     // ceil(50000/256)
#define NB_XB 4688      // ceil(50000*96/4/256)
#define NB_WPREP 640    // 8*20480/256
#define NB_PREP (NB_ZERO + NB_XB + NB_WPREP)

typedef __attribute__((ext_vector_type(8))) short short8;
typedef __attribute__((ext_vector_type(4))) float float4v;
typedef __attribute__((ext_vector_type(2))) unsigned uint2v;
typedef __attribute__((ext_vector_type(4))) unsigned uint4v;

__device__ __forceinline__ float bf2f(unsigned short h) {
    unsigned u = ((unsigned)h) << 16;
    float f;
    __builtin_memcpy(&f, &u, 4);
    return f;
}
__device__ __forceinline__ unsigned short f2bf(float f) {
    unsigned u;
    __builtin_memcpy(&u, &f, 4);
    unsigned r = (u + 0x7fffu + ((u >> 16) & 1u)) >> 16;  // RTNE
    return (unsigned short)r;
}
__device__ __forceinline__ float bf_lo(unsigned u) {
    unsigned v = u << 16;
    float f;
    __builtin_memcpy(&f, &v, 4);
    return f;
}
__device__ __forceinline__ float bf_hi(unsigned u) {
    unsigned v = u & 0xffff0000u;
    float f;
    __builtin_memcpy(&f, &v, 4);
    return f;
}

// ---------------- Fused prep: cursor zero + x->bf16 + weight prep ----------------
__global__ __launch_bounds__(256) void k_prep(int* __restrict__ cursor,
                                              const float* __restrict__ x,
                                              unsigned short* __restrict__ xb,
                                              const float* __restrict__ W1,
                                              const float* __restrict__ W2,
                                              const float* __restrict__ m1,
                                              const float* __restrict__ m2,
                                              unsigned short* __restrict__ wf) {
    int bid = blockIdx.x;
    if (bid < NB_ZERO) {
        int i = bid * 256 + threadIdx.x;
        if (i < N_NODES) cursor[i] = 0;
        return;
    }
    bid -= NB_ZERO;
    if (bid < NB_XB) {
        int i = bid * 256 + threadIdx.x;
        int idx = i * 4;
        if (idx < N_NODES * IN_F) {
            float4v v = __builtin_nontemporal_load((const float4v*)(x + idx));
            uint2v r;
            r.x = (unsigned)f2bf(v.x) | ((unsigned)f2bf(v.y) << 16);
            r.y = (unsigned)f2bf(v.z) | ((unsigned)f2bf(v.w) << 16);
            *(uint2v*)(xb + idx) = r;
        }
        return;
    }
    bid -= NB_XB;
    {
        int gid = bid * 256 + threadIdx.x;  // 8*20480 = 163840 total
        if (gid >= T_S * 20480) return;
        int t = gid / 20480;
        int idx = gid % 20480;
        float val;
        if (idx < 12288) {
            int j = idx & 7, lane = (idx >> 3) & 63, fr = idx >> 9;  // fr 0..23
            int kk = fr >> 3, nt = fr & 7;
            int k = kk * 32 + (lane >> 4) * 8 + j;
            int n = nt * 16 + (lane & 15);
            val = W1[k * HID_F + n] * m1[((size_t)t * IN_F + k) * HID_F + n];
        } else {
            int i2 = idx - 12288;
            int j = i2 & 7, lane = (i2 >> 3) & 63, fr = i2 >> 9;  // fr 0..15
            int kk = fr >> 2, ot = fr & 3;
            int k = kk * 32 + (lane >> 4) * 8 + j;
            int o = ot * 16 + (lane & 15);
            val = W2[k * OUT_F + o] * m2[((size_t)t * HID_F + k) * OUT_F + o];
        }
        wf[gid] = f2bf(val);
    }
}

// ---------------- Bucket fill (round-6 proven): 1 edge/thread, 8B nt-store ----------------
__global__ void k_fillB(const int* __restrict__ src, const int* __restrict__ dst,
                        const float* __restrict__ ew, int* __restrict__ cursor,
                        uint2v* __restrict__ bucket) {
    int e = blockIdx.x * 256 + threadIdx.x;
    if (e < N_EDGES) {
        int d = dst[e];
        int pos = atomicAdd(&cursor[d], 1);
        if (pos < CAP) {  // overflow guard (never taken for Poisson(16) input)
            uint2v c;
            c.x = (unsigned)src[e];
            c.y = __float_as_uint(ew[e]);
            __builtin_nontemporal_store(c, &bucket[(size_t)d * CAP + pos]);
        }
    }
}

// ---------------- SPMM1 (restructured): wave per node, 4 edges/instr via uint4 lanes ----------------
// Lane = (group g = lane>>4, d = lane&15); active lanes d<12 cover the 192B row as
// 12 x uint4. Each group handles one edge -> 4 edges per VMEM issue (4x fewer issues
// than dword-per-lane). Cross-group reduce: shfl_xor 16/32 (preserves d). Edge order
// within a node changes, but bucket order is already atomic-nondeterministic.
__global__ __launch_bounds__(256) void k_spmm1(const unsigned short* __restrict__ xb,
                                               const int* __restrict__ cursor,
                                               const uint2v* __restrict__ bucket,
                                               unsigned short* __restrict__ agg1) {
    int wave = threadIdx.x >> 6, lane = threadIdx.x & 63;
    int node = blockIdx.x * 4 + wave;
    int g = lane >> 4, d = lane & 15;
    int dd = (d < 12) ? d : 0;  // clamp inactive lanes to a safe address
    int cnt = cursor[node];
    if (cnt > CAP) cnt = CAP;
    int beg = node * CAP, end = beg + cnt;
    const uint4v* xrow = (const uint4v*)xb;  // 12 uint4 per 96-bf16 row
    float acc[8] = {0.f, 0.f, 0.f, 0.f, 0.f, 0.f, 0.f, 0.f};
    int e = beg;
    for (; e + 15 < end; e += 16) {
        uint2v c[4];
        uint4v dt[4];
#pragma unroll
        for (int i = 0; i < 4; i++) c[i] = bucket[e + i * 4 + g];
#pragma unroll
        for (int i = 0; i < 4; i++) dt[i] = xrow[(size_t)c[i].x * 12 + dd];
#pragma unroll
        for (int i = 0; i < 4; i++) {
            float wv = __uint_as_float(c[i].y);
            acc[0] = fmaf(wv, bf_lo(dt[i].x), acc[0]);
            acc[1] = fmaf(wv, bf_hi(dt[i].x), acc[1]);
            acc[2] = fmaf(wv, bf_lo(dt[i].y), acc[2]);
            acc[3] = fmaf(wv, bf_hi(dt[i].y), acc[3]);
            acc[4] = fmaf(wv, bf_lo(dt[i].z), acc[4]);
            acc[5] = fmaf(wv, bf_hi(dt[i].z), acc[5]);
            acc[6] = fmaf(wv, bf_lo(dt[i].w), acc[6]);
            acc[7] = fmaf(wv, bf_hi(dt[i].w), acc[7]);
        }
    }
    for (; e < end; e += 4) {
        int ee = e + g;
        bool ea = ee < end;
        uint2v c = bucket[ea ? ee : beg];
        float wv = ea ? __uint_as_float(c.y) : 0.f;
        uint4v dt = xrow[(size_t)c.x * 12 + dd];
        acc[0] = fmaf(wv, bf_lo(dt.x), acc[0]);
        acc[1] = fmaf(wv, bf_hi(dt.x), acc[1]);
        acc[2] = fmaf(wv, bf_lo(dt.y), acc[2]);
        acc[3] = fmaf(wv, bf_hi(dt.y), acc[3]);
        acc[4] = fmaf(wv, bf_lo(dt.z), acc[4]);
        acc[5] = fmaf(wv, bf_hi(dt.z), acc[5]);
        acc[6] = fmaf(wv, bf_lo(dt.w), acc[6]);
        acc[7] = fmaf(wv, bf_hi(dt.w), acc[7]);
    }
    // reduce across the 4 groups (lanes d, d+16, d+32, d+48)
#pragma unroll
    for (int j = 0; j < 8; j++) {
        acc[j] += __shfl_xor(acc[j], 16);
        acc[j] += __shfl_xor(acc[j], 32);
    }
    if (lane < 12) {  // g==0, d<12: store 16B of the 192B output row
        uint4v pk;
        pk.x = (unsigned)f2bf(acc[0]) | ((unsigned)f2bf(acc[1]) << 16);
        pk.y = (unsigned)f2bf(acc[2]) | ((unsigned)f2bf(acc[3]) << 16);
        pk.z = (unsigned)f2bf(acc[4]) | ((unsigned)f2bf(acc[5]) << 16);
        pk.w = (unsigned)f2bf(acc[6]) | ((unsigned)f2bf(acc[7]) << 16);
        ((uint4v*)agg1)[(size_t)node * 12 + d] = pk;
    }
}

// ------------- Fused GEMM (round-6 proven): W staged once, 8 node-groups/block -------------
__global__ __launch_bounds__(256) void k_gemm(const unsigned short* __restrict__ agg1,
                                              const unsigned short* __restrict__ wfrags,
                                              unsigned short* __restrict__ P, int tBase,
                                              int nodeStride, int tMul) {
    __shared__ __align__(16) unsigned short ldsW[20480];     // 40 KB
    __shared__ __align__(16) unsigned short ldsH[4][2176];   // 4 waves x [16][136] bf16
    int t = tBase + blockIdx.y;
    const uint4* wsrc = (const uint4*)(wfrags + (size_t)t * 20480);
    uint4* wdst = (uint4*)ldsW;
    for (int i = threadIdx.x; i < 2560; i += 256) wdst[i] = wsrc[i];
    __syncthreads();

    int wave = threadIdx.x >> 6, lane = threadIdx.x & 63;
    int quad = lane >> 4, l15 = lane & 15;

    for (int it = 0; it < 8; it++) {
        int node = blockIdx.x * 512 + it * 64 + wave * 16 + l15;
        bool v = node < N_NODES;

        short8 a[3];
        if (v) {
            const unsigned short* ap = agg1 + (size_t)node * IN_F;
            a[0] = *(const short8*)(ap + 0 * 32 + quad * 8);
            a[1] = *(const short8*)(ap + 1 * 32 + quad * 8);
            a[2] = *(const short8*)(ap + 2 * 32 + quad * 8);
        } else {
            short8 z = {0, 0, 0, 0, 0, 0, 0, 0};
            a[0] = z; a[1] = z; a[2] = z;
        }

        for (int nt = 0; nt < 8; nt++) {
            float4v acc = {0.f, 0.f, 0.f, 0.f};
            for (int kk = 0; kk < 3; kk++) {
                short8 w = *(const short8*)&ldsW[(kk * 8 + nt) * 512 + lane * 8];
                acc = __builtin_amdgcn_mfma_f32_16x16x32_bf16(w, a[kk], acc, 0, 0, 0);
            }
            unsigned h0 = f2bf(fmaxf(acc[0], 0.f));
            unsigned h1 = f2bf(fmaxf(acc[1], 0.f));
            unsigned h2 = f2bf(fmaxf(acc[2], 0.f));
            unsigned h3 = f2bf(fmaxf(acc[3], 0.f));
            uint2 pk;
            pk.x = h0 | (h1 << 16);
            pk.y = h2 | (h3 << 16);
            *(uint2*)&ldsH[wave][l15 * 136 + nt * 16 + quad * 4] = pk;
        }

        short8 hf[4];
        for (int kk = 0; kk < 4; kk++)
            hf[kk] = *(const short8*)&ldsH[wave][l15 * 136 + kk * 32 + quad * 8];

        unsigned short* Pt = P + (size_t)node * nodeStride + (size_t)t * tMul;
        for (int ot = 0; ot < 4; ot++) {
            float4v acc = {0.f, 0.f, 0.f, 0.f};
            for (int kk = 0; kk < 4; kk++) {
                short8 w = *(const short8*)&ldsW[12288 + (kk * 4 + ot) * 512 + lane * 8];
                acc = __builtin_amdgcn_mfma_f32_16x16x32_bf16(w, hf[kk], acc, 0, 0, 0);
            }
            if (v) {
                uint2 pk;
                pk.x = (unsigned)f2bf(acc[0]) | ((unsigned)f2bf(acc[1]) << 16);
                pk.y = (unsigned)f2bf(acc[2]) | ((unsigned)f2bf(acc[3]) << 16);
                *(uint2*)(Pt + ot * 16 + quad * 4) = pk;
            }
        }
    }
}

// ------------- SPMM2 batched (proven form): P [node][t][o], 1KB rows, wave/node -------------
__global__ __launch_bounds__(256) void k_spmm2(const unsigned short* __restrict__ P,
                                               const int* __restrict__ cursor,
                                               const uint2v* __restrict__ bucket,
                                               float* __restrict__ out) {
    int wave = threadIdx.x >> 6, lane = threadIdx.x & 63;
    int node = blockIdx.x * 4 + wave;
    int cnt = cursor[node];
    if (cnt > CAP) cnt = CAP;
    int beg = node * CAP, end = beg + cnt;
    const uint4v* Pl = (const uint4v*)P + lane;  // row = 64 uint4
    float acc[8] = {0.f, 0.f, 0.f, 0.f, 0.f, 0.f, 0.f, 0.f};
    int e = beg;
    for (; e + 7 < end; e += 8) {
        uint2v c[8];
        uint4v d[8];
#pragma unroll
        for (int i = 0; i < 8; i++) c[i] = bucket[e + i];
#pragma unroll
        for (int i = 0; i < 8; i++) d[i] = Pl[(size_t)c[i].x * 64];
#pragma unroll
        for (int i = 0; i < 8; i++) {
            float wv = __uint_as_float(c[i].y);
            acc[0] = fmaf(wv, bf_lo(d[i].x), acc[0]);
            acc[1] = fmaf(wv, bf_hi(d[i].x), acc[1]);
            acc[2] = fmaf(wv, bf_lo(d[i].y), acc[2]);
            acc[3] = fmaf(wv, bf_hi(d[i].y), acc[3]);
            acc[4] = fmaf(wv, bf_lo(d[i].z), acc[4]);
            acc[5] = fmaf(wv, bf_hi(d[i].z), acc[5]);
            acc[6] = fmaf(wv, bf_lo(d[i].w), acc[6]);
            acc[7] = fmaf(wv, bf_hi(d[i].w), acc[7]);
        }
    }
    for (; e + 3 < end; e += 4) {
        uint2v c[4];
        uint4v d[4];
#pragma unroll
        for (int i = 0; i < 4; i++) c[i] = bucket[e + i];
#pragma unroll
        for (int i = 0; i < 4; i++) d[i] = Pl[(size_t)c[i].x * 64];
#pragma unroll
        for (int i = 0; i < 4; i++) {
            float wv = __uint_as_float(c[i].y);
            acc[0] = fmaf(wv, bf_lo(d[i].x), acc[0]);
            acc[1] = fmaf(wv, bf_hi(d[i].x), acc[1]);
            acc[2] = fmaf(wv, bf_lo(d[i].y), acc[2]);
            acc[3] = fmaf(wv, bf_hi(d[i].y), acc[3]);
            acc[4] = fmaf(wv, bf_lo(d[i].z), acc[4]);
            acc[5] = fmaf(wv, bf_hi(d[i].z), acc[5]);
            acc[6] = fmaf(wv, bf_lo(d[i].w), acc[6]);
            acc[7] = fmaf(wv, bf_hi(d[i].w), acc[7]);
        }
    }
    for (; e < end; e++) {
        uint2v c = bucket[e];
        float wv = __uint_as_float(c.y);
        uint4v d = Pl[(size_t)c.x * 64];
        acc[0] = fmaf(wv, bf_lo(d.x), acc[0]);
        acc[1] = fmaf(wv, bf_hi(d.x), acc[1]);
        acc[2] = fmaf(wv, bf_lo(d.y), acc[2]);
        acc[3] = fmaf(wv, bf_hi(d.y), acc[3]);
        acc[4] = fmaf(wv, bf_lo(d.z), acc[4]);
        acc[5] = fmaf(wv, bf_hi(d.z), acc[5]);
        acc[6] = fmaf(wv, bf_lo(d.w), acc[6]);
        acc[7] = fmaf(wv, bf_hi(d.w), acc[7]);
    }
    // lane covers value indices lane*8..+7 of the [t][o] row: t = lane>>3, o = (lane&7)*8
    int t = lane >> 3, o = (lane & 7) * 8;
    float* op = out + ((size_t)t * N_NODES + node) * OUT_F + o;
    float4v v0 = {acc[0], acc[1], acc[2], acc[3]};
    float4v v1 = {acc[4], acc[5], acc[6], acc[7]};
    *(float4v*)op = v0;
    *(float4v*)(op + 4) = v1;
}

// per-sample fallback (small workspace): P layout [node][64]
__global__ __launch_bounds__(512) void k_spmm2_1t(const unsigned short* __restrict__ P,
                                                  const int* __restrict__ cursor,
                                                  const uint2v* __restrict__ bucket,
                                                  float* __restrict__ out) {
    int node = blockIdx.x * 8 + (threadIdx.x >> 6);
    int o = threadIdx.x & 63;
    if (node >= N_NODES) return;
    int cnt = cursor[node];
    if (cnt > CAP) cnt = CAP;
    int beg = node * CAP, end = beg + cnt;
    const unsigned short* Pt = P + o;
    float a0 = 0.f, a1 = 0.f, a2 = 0.f, a3 = 0.f;
    int e = beg;
    for (; e + 3 < end; e += 4) {
        uint2v c0 = bucket[e];
        uint2v c1 = bucket[e + 1];
        uint2v c2 = bucket[e + 2];
        uint2v c3 = bucket[e + 3];
        a0 += __uint_as_float(c0.y) * bf2f(Pt[(size_t)c0.x * OUT_F]);
        a1 += __uint_as_float(c1.y) * bf2f(Pt[(size_t)c1.x * OUT_F]);
        a2 += __uint_as_float(c2.y) * bf2f(Pt[(size_t)c2.x * OUT_F]);
        a3 += __uint_as_float(c3.y) * bf2f(Pt[(size_t)c3.x * OUT_F]);
    }
    for (; e < end; e++) {
        uint2v c = bucket[e];
        a0 += __uint_as_float(c.y) * bf2f(Pt[(size_t)c.x * OUT_F]);
    }
    out[(size_t)node * OUT_F + o] = a0 + a1 + a2 + a3;
}

extern "C" void kernel_launch(void* const* d_in, const int* in_sizes, int n_in,
                              void* d_out, int out_size, void* d_ws, size_t ws_size,
                              hipStream_t stream) {
    const float* x = (const float*)d_in[0];
    const float* ew = (const float*)d_in[1];
    const float* W1 = (const float*)d_in[2];
    const float* W2 = (const float*)d_in[3];
    const float* m1 = (const float*)d_in[4];
    const float* m2 = (const float*)d_in[5];
    const int* src = (const int*)d_in[6];
    const int* dst = (const int*)d_in[7];
    float* out = (float*)d_out;

    char* w = (char*)d_ws;
    size_t off = 0;
    auto alloc = [&](size_t bytes) -> void* {
        void* p = (void*)(w + off);
        off += (bytes + 255) & ~(size_t)255;
        return p;
    };
    int* cursor = (int*)alloc((size_t)N_NODES * 4);
    uint2v* bucket = (uint2v*)alloc((size_t)N_NODES * CAP * 8);  // 19.2 MB
    unsigned short* agg1 = (unsigned short*)alloc((size_t)N_NODES * IN_F * 2);
    unsigned short* wf = (unsigned short*)alloc((size_t)T_S * 20480 * 2);

    // union region: xb (9.6 MB, dead before k_gemm) overlaps P (51.2 MB batched)
    size_t unionBase = off;
    size_t pBytesBatched = (size_t)T_S * N_NODES * OUT_F * 2;
    size_t xbBytes = (size_t)N_NODES * IN_F * 2;
    bool batched = ws_size >= unionBase + (pBytesBatched > xbBytes ? pBytesBatched : xbBytes);
    unsigned short* xb = (unsigned short*)(w + unionBase);
    unsigned short* P = (unsigned short*)(w + unionBase);
    if (!batched) {
        xb = (unsigned short*)(w + unionBase);
        P = (unsigned short*)(w + unionBase + ((xbBytes + 255) & ~(size_t)255));
    }

    k_prep<<<NB_PREP, 256, 0, stream>>>(cursor, x, xb, W1, W2, m1, m2, wf);
    k_fillB<<<N_EDGES / 256, 256, 0, stream>>>(src, dst, ew, cursor, bucket);
    k_spmm1<<<N_NODES / 4, 256, 0, stream>>>(xb, cursor, bucket, agg1);

    if (batched) {
        k_gemm<<<dim3(98, 8), 256, 0, stream>>>(agg1, wf, P, 0, T_S * OUT_F, OUT_F);
        k_spmm2<<<N_NODES / 4, 256, 0, stream>>>(P, cursor, bucket, out);
    } else {
        for (int t = 0; t < T_S; t++) {
            k_gemm<<<dim3(98, 1), 256, 0, stream>>>(agg1, wf, P, t, OUT_F, 0);
            k_spmm2_1t<<<6250, 512, 0, stream>>>(P, cursor, bucket,
                                                 out + (size_t)t * N_NODES * OUT_F);
        }
    }
}